// Round 13
// baseline (142.983 us; speedup 1.0000x reference)
//
#include <hip/hip_runtime.h>
#include <hip/hip_bf16.h>
#include <cstddef>

// SpatialConv KERNEL_TYPE=0: 5-tap plus conv, N=16 Ci=Co=256 H=W=64, fp32 I/O.
// v9: v7 (weight-LDS deleted, a-frags from L2 regs, 1 barrier/chunk) with the
// a-register working set HALVED: load ks=0 frags (40 VGPR), compute half0,
// reload the same regs with ks=1 frags, compute half1. v7's a[2][KT][2]
// (80 VGPR live) + acc(128) + xr(24) overflowed the 256/wave cap of an
// 8-wave block. FIFO: a0 oldest -> x(24) younger -> half0 waits vmcnt(24)
// (x in flight); a1's wait drains x after ~2.6k cyc of MFMA cover (free).
// Tile: block = 256 o x 4 rows x 64 w, 8 waves, wave = 64 o x 2 rows.
#define N_  16
#define CI  256
#define CO  256
#define KT  5

#define XCELLS  1584          // one x buffer: 6 rows x 4 cg x 66 wp cells
#define XBUF_B  25344         // XCELLS * 16B

typedef __attribute__((ext_vector_type(8)))  short  short8;
typedef __attribute__((ext_vector_type(8)))  unsigned short ushort8;
typedef __attribute__((ext_vector_type(4)))  unsigned int uint4v;
typedef __attribute__((ext_vector_type(16))) float  floatx16;

static __device__ __forceinline__ unsigned short f2bf(float f) {
    union { float f; unsigned u; } v; v.f = f;
    unsigned r = v.u + 0x7fff + ((v.u >> 16) & 1);   // RNE
    return (unsigned short)(r >> 16);
}

// ---- prepass: w fp32 [Co][Ci][5] -> wb bf16, layout (elements):
//   idx = ((((k*8 + c)*2 + ks)*2 + lh)*256 + o)*8 + e,  ci = c*32+ks*16+lh*8+e
// element strides: e 1, o 8, lh 2048, ks 4096, c 8192, k 65536.  (== v3/v6/v7)
__global__ void wtrans_kernel(const float* __restrict__ w, unsigned short* __restrict__ wb) {
    int idx = blockIdx.x * 256 + threadIdx.x;
    if (idx >= KT * CO * CI) return;
    int e  = idx & 7;
    int o  = (idx >> 3) & 255;
    int lh = (idx >> 11) & 1;
    int ks = (idx >> 12) & 1;
    int c  = (idx >> 13) & 7;
    int k  = idx >> 16;
    int ci = c * 32 + ks * 16 + lh * 8 + e;
    wb[idx] = f2bf(w[(size_t)o * (CI * KT) + ci * KT + k]);
}

template<int KS>
static __device__ __forceinline__ void compute_half(const short8 (&a)[KT][2], const char* xB,
                                                    floatx16 (&acc)[2][2][2]) {
    #pragma unroll
    for (int k = 0; k < KT; ++k) {
        // taps (dy,dx): k0=(1,1) k1=(0,1) k2=(1,0) k3=(1,2) k4=(2,1)
        const int dy = (k == 1) ? 0 : (k == 4) ? 2 : 1;
        const int dx = (k == 2) ? 0 : (k == 3) ? 2 : 1;
        #pragma unroll
        for (int hr = 0; hr < 2; ++hr) {
            #pragma unroll
            for (int wh = 0; wh < 2; ++wh) {
                const short8 b = *(const short8*)(xB +
                    ((hr + dy) * 264 + KS * 132 + wh * 32 + dx) * 16);
                acc[0][hr][wh] = __builtin_amdgcn_mfma_f32_32x32x16_bf16(a[k][0], b, acc[0][hr][wh], 0, 0, 0);
                acc[1][hr][wh] = __builtin_amdgcn_mfma_f32_32x32x16_bf16(a[k][1], b, acc[1][hr][wh], 0, 0, 0);
            }
        }
    }
}

// ---- main: block = 256 o x 4 rows x 64 w, 8 waves; wave = 64 o x 2 rows ----
// x LDS: cell = buf*1584 + r*264 + cg*66 + wp (16B cells), r=0..5 -> image row
// h0+r-1, wp=w+1, pads zeroed.
__global__ __launch_bounds__(512, 2) void conv_mfma(const float* __restrict__ x,
                                                    const unsigned short* __restrict__ wb,
                                                    float* __restrict__ out) {
    __shared__ ushort8 lds[2 * XCELLS];   // 50688 B, x only

    const int tid = threadIdx.x;
    const int bx0 = blockIdx.x;
    const int bx  = (bx0 & 7) * 32 + (bx0 >> 3);   // XCD-bijective (256 = 8*32)
    const int hq  = bx & 15;                        // row-quad: rows 4hq..4hq+3
    const int n   = bx >> 4;
    const int h0  = hq * 4;

    const int lane    = tid & 63;
    const int wv      = tid >> 6;               // 0..7
    const int l31     = lane & 31;
    const int lh      = lane >> 5;
    const int owave   = (wv & 3) * 64;
    const int rowbase = (wv >> 2) * 2;          // wave rows: rowbase, rowbase+1

    const int sw  = tid & 63;
    const int scg = (tid >> 6) & 3;
    const int sr3 = tid >> 8;                   // 0/1: stages rows sr3*3 + {0,1,2}

    // zero horizontal pad cells (both x buffers): 2buf x 6r x 4cg x 2edge = 96
    if (tid < 96) {
        int buf = tid & 1;
        int wp  = ((tid >> 1) & 1) * 65;
        int cg  = (tid >> 2) & 3;
        int r   = tid >> 4;                     // 0..5
        lds[buf * XCELLS + r * 264 + cg * 66 + wp] = (ushort8)0;
    }

    const float* xn = x + (size_t)n * CI * 4096;

    // branchless edge handling: clamped row addr, zero-mask applied at pack.
    float zm[3];
    int   hcl[3];
    #pragma unroll
    for (int ii = 0; ii < 3; ++ii) {
        int hh = h0 - 1 + sr3 * 3 + ii;
        zm[ii]  = ((unsigned)hh < 64u) ? 1.f : 0.f;
        hcl[ii] = hh < 0 ? 0 : (hh > 63 ? 63 : hh);
    }

    float xr[3][8];
    auto load_chunk = [&](int c) {
        #pragma unroll
        for (int ii = 0; ii < 3; ++ii) {
            const float* p = xn + (c * 32 + scg * 8) * 4096 + hcl[ii] * 64 + sw;
            #pragma unroll
            for (int e = 0; e < 8; ++e) xr[ii][e] = p[e * 4096];
        }
    };
    auto write_chunk = [&](int b) {
        #pragma unroll
        for (int ii = 0; ii < 3; ++ii) {
            const int i = sr3 * 3 + ii;
            uint4v v;
            #pragma unroll
            for (int e = 0; e < 4; ++e) {
                __hip_bfloat162 pk = __float22bfloat162_rn(
                    make_float2(zm[ii] * xr[ii][2 * e], zm[ii] * xr[ii][2 * e + 1]));
                union { __hip_bfloat162 h; unsigned u; } cv; cv.h = pk;
                v[e] = cv.u;
            }
            *(uint4v*)&lds[b * XCELLS + i * 264 + scg * 66 + (sw + 1)] = v;
        }
    };

    floatx16 acc[2][2][2];                       // [o-tile][h-row][w-half]
    #pragma unroll
    for (int ot = 0; ot < 2; ++ot)
        #pragma unroll
        for (int hr = 0; hr < 2; ++hr)
            #pragma unroll
            for (int wh = 0; wh < 2; ++wh)
                #pragma unroll
                for (int e = 0; e < 16; ++e) acc[ot][hr][wh][e] = 0.f;

    const char* xbase = (const char*)lds + rowbase * 4224 + lh * 1056 + l31 * 16;
    // a-frag lane base (elements): each load = 2x512B contiguous segments (v3)
    const unsigned short* wA = wb + lh * 2048 + (owave + l31) * 8;

    load_chunk(0);
    write_chunk(0);
    __syncthreads();

    for (int c = 0; c < 8; ++c) {
        const char* xb = xbase + (c & 1) * XBUF_B;
        const unsigned short* wc = wA + c * 8192;

        // 1) ks=0 a-frags -> regs (oldest in vmcnt FIFO; 10 loads, 40 VGPR)
        short8 a[KT][2];
        #pragma unroll
        for (int k = 0; k < KT; ++k)
            #pragma unroll
            for (int ot = 0; ot < 2; ++ot)
                a[k][ot] = *(const short8*)(wc + k * 65536 + ot * 256);
        __builtin_amdgcn_sched_barrier(0);

        // 2) x prefetch for next chunk (younger: half0's a-wait keeps these in flight)
        if (c < 7) load_chunk(c + 1);
        __builtin_amdgcn_sched_barrier(0);

        // 3) half0: b from LDS, a from regs (compiler wait = vmcnt(24))
        compute_half<0>(a, xb, acc);
        __builtin_amdgcn_sched_barrier(0);

        // 4) ks=1 a-frags into the SAME regs; their wait drains x too, but x
        //    has had the whole half0 (~2.6k cyc) of cover vs ~900 cyc latency.
        #pragma unroll
        for (int k = 0; k < KT; ++k)
            #pragma unroll
            for (int ot = 0; ot < 2; ++ot)
                a[k][ot] = *(const short8*)(wc + k * 65536 + 4096 + ot * 256);
        compute_half<1>(a, xb, acc);
        __builtin_amdgcn_sched_barrier(0);

        // 5) stage x for next chunk into the other buffer, single barrier
        if (c < 7) write_chunk((c + 1) & 1);
        __syncthreads();
    }

    // epilogue: C/D: col(px) = l31, row(o-off) = (reg&3) + 8*(reg>>2) + 4*lh
    #pragma unroll
    for (int ot = 0; ot < 2; ++ot) {
        #pragma unroll
        for (int hr = 0; hr < 2; ++hr) {
            const int h = h0 + rowbase + hr;
            #pragma unroll
            for (int wh = 0; wh < 2; ++wh) {
                #pragma unroll
                for (int reg = 0; reg < 16; ++reg) {
                    int o = owave + ot * 32 + (reg & 3) + 8 * (reg >> 2) + 4 * lh;
                    out[(((size_t)n * CO + o) * 64 + h) * 64 + wh * 32 + l31] = acc[ot][hr][wh][reg];
                }
            }
        }
    }
}

extern "C" void kernel_launch(void* const* d_in, const int* in_sizes, int n_in,
                              void* d_out, int out_size, void* d_ws, size_t ws_size,
                              hipStream_t stream) {
    const float* x = (const float*)d_in[0];
    const float* w = (const float*)d_in[1];
    float* out = (float*)d_out;

    unsigned short* wb = (unsigned short*)d_ws;    // 640 KB, the only workspace

    wtrans_kernel<<<dim3((KT * CO * CI + 255) / 256), dim3(256), 0, stream>>>(w, wb);
    conv_mfma<<<dim3(N_ * 16), dim3(512), 0, stream>>>(x, wb, out);
}

// Round 14
// 140.750 us; speedup vs baseline: 1.0159x; 1.0159x over previous
//
#include <hip/hip_runtime.h>
#include <hip/hip_bf16.h>
#include <cstddef>

// SpatialConv KERNEL_TYPE=0: 5-tap plus conv, N=16 Ci=Co=256 H=W=64, fp32 I/O.
// v10: v9 halved in h -> TWO independent 4-wave blocks per CU. v4b/v6/v9 all
// landed at 56-60us regardless of barrier/weight-path structure: one 8-wave
// lockstep domain at 2 waves/SIMD has correlated stalls and the SIMD idles
// (MfmaUtil 29% = exactly the MFMA floor; rest is exposure). m97-GEMM regime:
// multiple co-resident blocks give implicit overlap. Tile 256o x 2 rows,
// block = 4 waves (wave = 64o x 2rows, acc/a/frag economy IDENTICAL to v9),
// grid = 16n x 32hp = 512 = 2 blocks/CU (LDS 33.8KB, 8 waves/CU). Weight
// fetch per CU unchanged (no o-dup); x halo 1.33x (L3-absorbed).
#define N_  16
#define CI  256
#define CO  256
#define KT  5

#define XCELLS  1056          // one x buffer: 4 rows x 4 cg x 66 wp cells
#define XBUF_B  16896         // XCELLS * 16B

typedef __attribute__((ext_vector_type(8)))  short  short8;
typedef __attribute__((ext_vector_type(8)))  unsigned short ushort8;
typedef __attribute__((ext_vector_type(4)))  unsigned int uint4v;
typedef __attribute__((ext_vector_type(16))) float  floatx16;

static __device__ __forceinline__ unsigned short f2bf(float f) {
    union { float f; unsigned u; } v; v.f = f;
    unsigned r = v.u + 0x7fff + ((v.u >> 16) & 1);   // RNE
    return (unsigned short)(r >> 16);
}

// ---- prepass: w fp32 [Co][Ci][5] -> wb bf16, layout (elements):
//   idx = ((((k*8 + c)*2 + ks)*2 + lh)*256 + o)*8 + e,  ci = c*32+ks*16+lh*8+e
// element strides: e 1, o 8, lh 2048, ks 4096, c 8192, k 65536.  (== v3/v6/v9)
__global__ void wtrans_kernel(const float* __restrict__ w, unsigned short* __restrict__ wb) {
    int idx = blockIdx.x * 256 + threadIdx.x;
    if (idx >= KT * CO * CI) return;
    int e  = idx & 7;
    int o  = (idx >> 3) & 255;
    int lh = (idx >> 11) & 1;
    int ks = (idx >> 12) & 1;
    int c  = (idx >> 13) & 7;
    int k  = idx >> 16;
    int ci = c * 32 + ks * 16 + lh * 8 + e;
    wb[idx] = f2bf(w[(size_t)o * (CI * KT) + ci * KT + k]);
}

template<int KS>
static __device__ __forceinline__ void compute_half(const short8 (&a)[KT][2], const char* xB,
                                                    floatx16 (&acc)[2][2][2]) {
    #pragma unroll
    for (int k = 0; k < KT; ++k) {
        // taps (dy,dx): k0=(1,1) k1=(0,1) k2=(1,0) k3=(1,2) k4=(2,1)
        const int dy = (k == 1) ? 0 : (k == 4) ? 2 : 1;
        const int dx = (k == 2) ? 0 : (k == 3) ? 2 : 1;
        #pragma unroll
        for (int hr = 0; hr < 2; ++hr) {
            #pragma unroll
            for (int wh = 0; wh < 2; ++wh) {
                const short8 b = *(const short8*)(xB +
                    ((hr + dy) * 264 + KS * 132 + wh * 32 + dx) * 16);
                acc[0][hr][wh] = __builtin_amdgcn_mfma_f32_32x32x16_bf16(a[k][0], b, acc[0][hr][wh], 0, 0, 0);
                acc[1][hr][wh] = __builtin_amdgcn_mfma_f32_32x32x16_bf16(a[k][1], b, acc[1][hr][wh], 0, 0, 0);
            }
        }
    }
}

// ---- main: block = 256 o x 2 rows x 64 w, 4 waves; wave = 64 o x 2 rows ----
// x LDS: cell = buf*1056 + r*264 + cg*66 + wp (16B cells), r=0..3 -> image row
// h0+r-1, wp=w+1, pads zeroed.
__global__ __launch_bounds__(256, 2) void conv_mfma(const float* __restrict__ x,
                                                    const unsigned short* __restrict__ wb,
                                                    float* __restrict__ out) {
    __shared__ ushort8 lds[2 * XCELLS];   // 33792 B, x only

    const int tid = threadIdx.x;
    const int bx0 = blockIdx.x;
    const int bx  = (bx0 & 7) * 64 + (bx0 >> 3);   // XCD-bijective (512 = 8*64)
    const int g   = bx & 31;                        // row-pair: rows 2g, 2g+1
    const int n   = bx >> 5;
    const int h0  = g * 2;

    const int lane  = tid & 63;
    const int wv    = tid >> 6;                 // 0..3 = o-group
    const int l31   = lane & 31;
    const int lh    = lane >> 5;
    const int owave = wv * 64;

    const int sw  = tid & 63;
    const int scg = (tid >> 6) & 3;             // each thread stages all 4 rows

    // zero horizontal pad cells (both x buffers): 2buf x 4r x 4cg x 2edge = 64
    if (tid < 64) {
        int buf = tid & 1;
        int wp  = ((tid >> 1) & 1) * 65;
        int cg  = (tid >> 2) & 3;
        int r   = (tid >> 4) & 3;               // 0..3
        lds[buf * XCELLS + r * 264 + cg * 66 + wp] = (ushort8)0;
    }

    const float* xn = x + (size_t)n * CI * 4096;

    // branchless edge handling: clamped row addr, zero-mask applied at pack.
    float zm[4];
    int   hcl[4];
    #pragma unroll
    for (int ii = 0; ii < 4; ++ii) {
        int hh = h0 - 1 + ii;
        zm[ii]  = ((unsigned)hh < 64u) ? 1.f : 0.f;
        hcl[ii] = hh < 0 ? 0 : (hh > 63 ? 63 : hh);
    }

    float xr[4][8];
    auto load_chunk = [&](int c) {
        #pragma unroll
        for (int ii = 0; ii < 4; ++ii) {
            const float* p = xn + (c * 32 + scg * 8) * 4096 + hcl[ii] * 64 + sw;
            #pragma unroll
            for (int e = 0; e < 8; ++e) xr[ii][e] = p[e * 4096];
        }
    };
    auto write_chunk = [&](int b) {
        #pragma unroll
        for (int ii = 0; ii < 4; ++ii) {
            uint4v v;
            #pragma unroll
            for (int e = 0; e < 4; ++e) {
                __hip_bfloat162 pk = __float22bfloat162_rn(
                    make_float2(zm[ii] * xr[ii][2 * e], zm[ii] * xr[ii][2 * e + 1]));
                union { __hip_bfloat162 h; unsigned u; } cv; cv.h = pk;
                v[e] = cv.u;
            }
            *(uint4v*)&lds[b * XCELLS + ii * 264 + scg * 66 + (sw + 1)] = v;
        }
    };

    floatx16 acc[2][2][2];                       // [o-tile][h-row][w-half]
    #pragma unroll
    for (int ot = 0; ot < 2; ++ot)
        #pragma unroll
        for (int hr = 0; hr < 2; ++hr)
            #pragma unroll
            for (int wh = 0; wh < 2; ++wh)
                #pragma unroll
                for (int e = 0; e < 16; ++e) acc[ot][hr][wh][e] = 0.f;

    const char* xbase = (const char*)lds + lh * 1056 + l31 * 16;
    // a-frag lane base (elements): each load = 2x512B contiguous segments (v3)
    const unsigned short* wA = wb + lh * 2048 + (owave + l31) * 8;

    load_chunk(0);
    write_chunk(0);
    __syncthreads();

    for (int c = 0; c < 8; ++c) {
        const char* xb = xbase + (c & 1) * XBUF_B;
        const unsigned short* wc = wA + c * 8192;

        // 1) ks=0 a-frags -> regs (oldest in vmcnt FIFO; 10 loads, 40 VGPR)
        short8 a[KT][2];
        #pragma unroll
        for (int k = 0; k < KT; ++k)
            #pragma unroll
            for (int ot = 0; ot < 2; ++ot)
                a[k][ot] = *(const short8*)(wc + k * 65536 + ot * 256);
        __builtin_amdgcn_sched_barrier(0);

        // 2) x prefetch for next chunk (younger: half0's a-wait keeps these in flight)
        if (c < 7) load_chunk(c + 1);
        __builtin_amdgcn_sched_barrier(0);

        // 3) half0: b from LDS, a from regs (compiler wait = vmcnt(32))
        compute_half<0>(a, xb, acc);
        __builtin_amdgcn_sched_barrier(0);

        // 4) ks=1 a-frags into the SAME regs; their wait drains x too -- any
        //    exposure is covered by the SIBLING block on this CU (the point).
        #pragma unroll
        for (int k = 0; k < KT; ++k)
            #pragma unroll
            for (int ot = 0; ot < 2; ++ot)
                a[k][ot] = *(const short8*)(wc + k * 65536 + 4096 + ot * 256);
        compute_half<1>(a, xb, acc);
        __builtin_amdgcn_sched_barrier(0);

        // 5) stage x for next chunk into the other buffer, single barrier
        if (c < 7) write_chunk((c + 1) & 1);
        __syncthreads();
    }

    // epilogue: C/D: col(px) = l31, row(o-off) = (reg&3) + 8*(reg>>2) + 4*lh
    #pragma unroll
    for (int ot = 0; ot < 2; ++ot) {
        #pragma unroll
        for (int hr = 0; hr < 2; ++hr) {
            const int h = h0 + hr;
            #pragma unroll
            for (int wh = 0; wh < 2; ++wh) {
                #pragma unroll
                for (int reg = 0; reg < 16; ++reg) {
                    int o = owave + ot * 32 + (reg & 3) + 8 * (reg >> 2) + 4 * lh;
                    out[(((size_t)n * CO + o) * 64 + h) * 64 + wh * 32 + l31] = acc[ot][hr][wh][reg];
                }
            }
        }
    }
}

extern "C" void kernel_launch(void* const* d_in, const int* in_sizes, int n_in,
                              void* d_out, int out_size, void* d_ws, size_t ws_size,
                              hipStream_t stream) {
    const float* x = (const float*)d_in[0];
    const float* w = (const float*)d_in[1];
    float* out = (float*)d_out;

    unsigned short* wb = (unsigned short*)d_ws;    // 640 KB, the only workspace

    wtrans_kernel<<<dim3((KT * CO * CI + 255) / 256), dim3(256), 0, stream>>>(w, wb);
    conv_mfma<<<dim3(N_ * 32), dim3(256), 0, stream>>>(x, wb, out);
}